// Round 1
// baseline (1390.416 us; speedup 1.0000x reference)
//
#include <hip/hip_runtime.h>
#include <hip/hip_fp16.h>

#define NN 200000
#define EE 3200000
#define HID 32
#define SB 782            // ceil(NN/256) scan blocks

// ---------------- fp16 pack helpers (4 halfs <-> float4, 8B memory op) ------

__device__ inline float4 ld_h4(const __half* p) {
    uint2 u = *reinterpret_cast<const uint2*>(p);
    __half2 a = *reinterpret_cast<__half2*>(&u.x);
    __half2 b = *reinterpret_cast<__half2*>(&u.y);
    float2 fa = __half22float2(a), fb = __half22float2(b);
    return make_float4(fa.x, fa.y, fb.x, fb.y);
}

__device__ inline void st_h4(__half* p, float4 v) {
    __half2 a = __floats2half2_rn(v.x, v.y);
    __half2 b = __floats2half2_rn(v.z, v.w);
    uint2 u;
    u.x = *reinterpret_cast<unsigned*>(&a);
    u.y = *reinterpret_cast<unsigned*>(&b);
    *reinterpret_cast<uint2*>(p) = u;
}

// ---------------- degrees via device-scope atomics (single 25.6MB pass) -----

__global__ __launch_bounds__(256) void k_zero(int* __restrict__ p, int n) {
    int i = blockIdx.x * 256 + threadIdx.x;
    if (i < n) p[i] = 0;
}

// grid = EE/4/256 = 3125 exactly; each thread handles 4 src + 4 dst
__global__ __launch_bounds__(256) void k_deg(const int* __restrict__ ei,
                                             int* __restrict__ dsrc,
                                             int* __restrict__ ddst) {
    int t = blockIdx.x * 256 + threadIdx.x;
    const int4* s4 = reinterpret_cast<const int4*>(ei);
    const int4* d4 = reinterpret_cast<const int4*>(ei + EE);
    int4 s = s4[t];
    atomicAdd(&dsrc[s.x], 1); atomicAdd(&dsrc[s.y], 1);
    atomicAdd(&dsrc[s.z], 1); atomicAdd(&dsrc[s.w], 1);
    int4 d = d4[t];
    atomicAdd(&ddst[d.x], 1); atomicAdd(&ddst[d.y], 1);
    atomicAdd(&ddst[d.z], 1); atomicAdd(&ddst[d.w], 1);
}

__global__ void k_dinv(const int* __restrict__ dsrc, float* __restrict__ dinv) {
    int i = blockIdx.x * 256 + threadIdx.x;
    if (i < NN) {
        int d = dsrc[i];
        dinv[i] = d > 0 ? rsqrtf((float)d) : 0.f;
    }
}

// ---------------- exclusive scan of ddst -> rowptr (+cursor copy) -----------

__global__ void k_ssum(const int* __restrict__ ddst, int* __restrict__ bsum) {
    __shared__ int s[256];
    int i = blockIdx.x * 256 + threadIdx.x;
    s[threadIdx.x] = (i < NN) ? ddst[i] : 0;
    __syncthreads();
    for (int off = 128; off > 0; off >>= 1) {
        if (threadIdx.x < off) s[threadIdx.x] += s[threadIdx.x + off];
        __syncthreads();
    }
    if (threadIdx.x == 0) bsum[blockIdx.x] = s[0];
}

__global__ void k_sscan(const int* __restrict__ bsum, int* __restrict__ bbase) {
    __shared__ int s[256];
    __shared__ int carry;
    if (threadIdx.x == 0) carry = 0;
    __syncthreads();
    for (int base = 0; base < SB; base += 256) {
        int k = base + threadIdx.x;
        int v = (k < SB) ? bsum[k] : 0;
        s[threadIdx.x] = v;
        __syncthreads();
        for (int off = 1; off < 256; off <<= 1) {
            int t = (threadIdx.x >= off) ? s[threadIdx.x - off] : 0;
            __syncthreads();
            s[threadIdx.x] += t;
            __syncthreads();
        }
        int excl = s[threadIdx.x] - v + carry;
        if (k < SB) bbase[k] = excl;
        __syncthreads();
        if (threadIdx.x == 0) carry += s[255];
        __syncthreads();
    }
}

__global__ void k_sout(const int* __restrict__ ddst, const int* __restrict__ bbase,
                       int* __restrict__ rowptr, int* __restrict__ cursor) {
    __shared__ int s[256];
    int i = blockIdx.x * 256 + threadIdx.x;
    int v = (i < NN) ? ddst[i] : 0;
    s[threadIdx.x] = v;
    __syncthreads();
    for (int off = 1; off < 256; off <<= 1) {
        int t = (threadIdx.x >= off) ? s[threadIdx.x - off] : 0;
        __syncthreads();
        s[threadIdx.x] += t;
        __syncthreads();
    }
    int excl = s[threadIdx.x] - v + bbase[blockIdx.x];
    if (i < NN) { rowptr[i] = excl; cursor[i] = excl; }
    if (i == NN - 1) rowptr[NN] = EE;
}

// ---------------- direct exact-CSR scatter (full occupancy) -----------------
// grid = EE/4/256 = 3125; pos = atomicAdd(cursor[dst]); csr[pos] = (src, w)

__global__ __launch_bounds__(256) void k_scatter2(const int* __restrict__ ei,
                                                  const float* __restrict__ dinv,
                                                  int* __restrict__ cursor,
                                                  int2* __restrict__ csr) {
    int t = blockIdx.x * 256 + threadIdx.x;
    const int4* s4 = reinterpret_cast<const int4*>(ei);
    const int4* d4 = reinterpret_cast<const int4*>(ei + EE);
    int4 s = s4[t];
    int4 d = d4[t];
    float w0 = -dinv[s.x] * dinv[d.x];
    float w1 = -dinv[s.y] * dinv[d.y];
    float w2 = -dinv[s.z] * dinv[d.z];
    float w3 = -dinv[s.w] * dinv[d.w];
    int p0 = atomicAdd(&cursor[d.x], 1);
    int p1 = atomicAdd(&cursor[d.y], 1);
    int p2 = atomicAdd(&cursor[d.z], 1);
    int p3 = atomicAdd(&cursor[d.w], 1);
    csr[p0] = make_int2(s.x, __float_as_int(w0));
    csr[p1] = make_int2(s.y, __float_as_int(w1));
    csr[p2] = make_int2(s.z, __float_as_int(w2));
    csr[p3] = make_int2(s.w, __float_as_int(w3));
}

// ---------------- input MLP: h = relu(x @ W0 + b0), fp16 out ----------------

__global__ void k_mlp0(const float* __restrict__ x, const float* __restrict__ W0,
                       const float* __restrict__ b0, __half* __restrict__ out) {
    int t = blockIdx.x * 256 + threadIdx.x;   // t = n*32 + o
    int n = t >> 5, o = t & 31;
    if (n < NN) {
        float acc = b0[o];
#pragma unroll
        for (int i = 0; i < 3; i++) acc += x[n * 3 + i] * W0[i * 32 + o];
        out[t] = __float2half(fmaxf(acc, 0.f));
    }
}

// ---------------- propagation (CSR, gather-only, fp16 features) -------------
// 8 threads/node, 4 halfs (8B) per thread => 1 cache line per edge row.

__global__ __launch_bounds__(256) void k_prop_csr(const int* __restrict__ rowptr,
                                                  const int2* __restrict__ csr,
                                                  const __half* __restrict__ x,
                                                  __half* __restrict__ y) {
    int t = blockIdx.x * 256 + threadIdx.x;
    int n = t >> 3, c = t & 7;
    if (n >= NN) return;
    int beg = rowptr[n], end = rowptr[n + 1];
    float4 acc = make_float4(0.f, 0.f, 0.f, 0.f);
    int j = beg;
    const __half* xc = x + (size_t)c * 4;
    for (; j + 8 <= end; j += 8) {
        int2 e0 = csr[j + 0], e1 = csr[j + 1], e2 = csr[j + 2], e3 = csr[j + 3];
        int2 e4 = csr[j + 4], e5 = csr[j + 5], e6 = csr[j + 6], e7 = csr[j + 7];
        float4 v0 = ld_h4(xc + (size_t)e0.x * 32);
        float4 v1 = ld_h4(xc + (size_t)e1.x * 32);
        float4 v2 = ld_h4(xc + (size_t)e2.x * 32);
        float4 v3 = ld_h4(xc + (size_t)e3.x * 32);
        float4 v4 = ld_h4(xc + (size_t)e4.x * 32);
        float4 v5 = ld_h4(xc + (size_t)e5.x * 32);
        float4 v6 = ld_h4(xc + (size_t)e6.x * 32);
        float4 v7 = ld_h4(xc + (size_t)e7.x * 32);
        float w0 = __int_as_float(e0.y), w1 = __int_as_float(e1.y);
        float w2 = __int_as_float(e2.y), w3 = __int_as_float(e3.y);
        float w4 = __int_as_float(e4.y), w5 = __int_as_float(e5.y);
        float w6 = __int_as_float(e6.y), w7 = __int_as_float(e7.y);
        acc.x += w0 * v0.x + w1 * v1.x + w2 * v2.x + w3 * v3.x
               + w4 * v4.x + w5 * v5.x + w6 * v6.x + w7 * v7.x;
        acc.y += w0 * v0.y + w1 * v1.y + w2 * v2.y + w3 * v3.y
               + w4 * v4.y + w5 * v5.y + w6 * v6.y + w7 * v7.y;
        acc.z += w0 * v0.z + w1 * v1.z + w2 * v2.z + w3 * v3.z
               + w4 * v4.z + w5 * v5.z + w6 * v6.z + w7 * v7.z;
        acc.w += w0 * v0.w + w1 * v1.w + w2 * v2.w + w3 * v3.w
               + w4 * v4.w + w5 * v5.w + w6 * v6.w + w7 * v7.w;
    }
    for (; j + 4 <= end; j += 4) {
        int2 e0 = csr[j + 0], e1 = csr[j + 1], e2 = csr[j + 2], e3 = csr[j + 3];
        float4 v0 = ld_h4(xc + (size_t)e0.x * 32);
        float4 v1 = ld_h4(xc + (size_t)e1.x * 32);
        float4 v2 = ld_h4(xc + (size_t)e2.x * 32);
        float4 v3 = ld_h4(xc + (size_t)e3.x * 32);
        float w0 = __int_as_float(e0.y), w1 = __int_as_float(e1.y);
        float w2 = __int_as_float(e2.y), w3 = __int_as_float(e3.y);
        acc.x += w0 * v0.x + w1 * v1.x + w2 * v2.x + w3 * v3.x;
        acc.y += w0 * v0.y + w1 * v1.y + w2 * v2.y + w3 * v3.y;
        acc.z += w0 * v0.z + w1 * v1.z + w2 * v2.z + w3 * v3.z;
        acc.w += w0 * v0.w + w1 * v1.w + w2 * v2.w + w3 * v3.w;
    }
    for (; j < end; j++) {
        int2 e = csr[j];
        float w = __int_as_float(e.y);
        float4 v = ld_h4(xc + (size_t)e.x * 32);
        acc.x += w * v.x; acc.y += w * v.y; acc.z += w * v.z; acc.w += w * v.w;
    }
    st_h4(y + (size_t)n * 32 + c * 4, acc);
}

// ---------------- fused Cheb combine (fp16 I/O, fp32 math) ----------------

__global__ void k_cheb(const __half* T0, const __half* P1, const __half* P2,
                       const __half* res, __half* out,
                       const float* __restrict__ W, const float* __restrict__ b,
                       int do_relu, int has_res) {
    __shared__ float sT0[8][32], sP1[8][32], sP2[8][32], sR[8][32];
    int t = threadIdx.x;
    int nl = t >> 5, o = t & 31;
    int gi = blockIdx.x * 256 + t;
    sT0[nl][o] = __half2float(T0[gi]);
    sP1[nl][o] = __half2float(P1[gi]);
    sP2[nl][o] = __half2float(P2[gi]);
    sR[nl][o] = has_res ? __half2float(res[gi]) : 0.f;
    __syncthreads();
    float acc = b[o] + sR[nl][o];
#pragma unroll
    for (int i = 0; i < 32; i++) {
        float w0 = W[i * 32 + o];
        float w1 = W[1024 + i * 32 + o];
        float w2 = W[2048 + i * 32 + o];
        float t0 = sT0[nl][i];
        acc += t0 * w0 + sP1[nl][i] * w1 + (2.f * sP2[nl][i] - t0) * w2;
    }
    if (do_relu) acc = fmaxf(acc, 0.f);
    out[gi] = __float2half(acc);
}

// ---------------- final head: out = X @ W1 + b1 (fp16 in, fp32 out) ---------

__global__ void k_final(const __half* __restrict__ X, const float* __restrict__ W1,
                        const float* __restrict__ b1, float* __restrict__ out) {
    int n = blockIdx.x * 256 + threadIdx.x;
    if (n < NN) {
        float acc = b1[0];
        const __half* xp = X + (size_t)n * 32;
#pragma unroll
        for (int c = 0; c < 8; c++) {
            float4 v = ld_h4(xp + c * 4);
            acc += v.x * W1[c * 4 + 0] + v.y * W1[c * 4 + 1] +
                   v.z * W1[c * 4 + 2] + v.w * W1[c * 4 + 3];
        }
        out[n] = acc;
    }
}

extern "C" void kernel_launch(void* const* d_in, const int* in_sizes, int n_in,
                              void* d_out, int out_size, void* d_ws, size_t ws_size,
                              hipStream_t stream) {
    const float* x    = (const float*)d_in[0];
    const int*   ei   = (const int*)d_in[1];
    const float* W0   = (const float*)d_in[2];
    const float* b0   = (const float*)d_in[3];
    const float* c11W = (const float*)d_in[4];
    const float* c11b = (const float*)d_in[5];
    const float* c12W = (const float*)d_in[6];
    const float* c12b = (const float*)d_in[7];
    const float* c21W = (const float*)d_in[8];
    const float* c21b = (const float*)d_in[9];
    const float* c22W = (const float*)d_in[10];
    const float* c22b = (const float*)d_in[11];
    const float* W1   = (const float*)d_in[12];
    const float* b1   = (const float*)d_in[13];
    float* out = (float*)d_out;

    char* ws = (char*)d_ws;
    int* dsrc = (int*)ws;     ws += (size_t)NN * 4;   // dsrc+ddst contiguous
    int* ddst = (int*)ws;     ws += (size_t)NN * 4;   // (one k_zero covers both)
    float* dinv = (float*)ws; ws += (size_t)NN * 4;
    int* rowptr = (int*)ws;   ws += (size_t)(NN + 1) * 4;
    int* cursor = (int*)ws;   ws += (size_t)NN * 4;
    int* bsum = (int*)ws;     ws += (size_t)(SB + 1) * 4;
    int* bbase = (int*)ws;    ws += (size_t)(SB + 1) * 4;
    ws = (char*)(((uintptr_t)ws + 15) & ~(uintptr_t)15);
    int2* csr = (int2*)ws;    ws += (size_t)EE * 8;              // 25.6 MB
    __half* F0 = (__half*)ws; ws += (size_t)NN * HID * 2;
    __half* F1 = (__half*)ws; ws += (size_t)NN * HID * 2;
    __half* P1 = (__half*)ws; ws += (size_t)NN * HID * 2;
    __half* P2 = (__half*)ws; ws += (size_t)NN * HID * 2;

    // degrees (src for dinv, dst for CSR rowptr) in one pass
    k_zero<<<(2 * NN + 255) / 256, 256, 0, stream>>>(dsrc, 2 * NN);
    k_deg<<<EE / 1024, 256, 0, stream>>>(ei, dsrc, ddst);
    k_dinv<<<(NN + 255) / 256, 256, 0, stream>>>(dsrc, dinv);

    // exclusive scan ddst -> rowptr, cursor
    k_ssum<<<SB, 256, 0, stream>>>(ddst, bsum);
    k_sscan<<<1, 256, 0, stream>>>(bsum, bbase);
    k_sout<<<SB, 256, 0, stream>>>(ddst, bbase, rowptr, cursor);

    // exact-CSR direct scatter
    k_scatter2<<<EE / 1024, 256, 0, stream>>>(ei, dinv, cursor, csr);

    k_mlp0<<<NN * HID / 256, 256, 0, stream>>>(x, W0, b0, F0);

    auto conv = [&](const __half* T0, const __half* res, __half* outb,
                    const float* W, const float* b, int relu, int has_res) {
        k_prop_csr<<<NN * 8 / 256, 256, 0, stream>>>(rowptr, csr, T0, P1);
        k_prop_csr<<<NN * 8 / 256, 256, 0, stream>>>(rowptr, csr, P1, P2);
        k_cheb<<<NN / 8, 256, 0, stream>>>(T0, P1, P2, res, outb, W, b, relu, has_res);
    };

    conv(F0, nullptr, F1, c11W, c11b, 1, 0);   // block1 conv1: relu
    conv(F1, F0,      F0, c12W, c12b, 1, 1);   // block1 conv2: +res, relu
    conv(F0, nullptr, F1, c21W, c21b, 1, 0);   // block2 conv1: relu
    conv(F1, F0,      F0, c22W, c22b, 1, 1);   // block2 conv2: +res, relu

    k_final<<<(NN + 255) / 256, 256, 0, stream>>>(F0, W1, b1, out);
}